// Round 1
// baseline (2624.261 us; speedup 1.0000x reference)
//
#include <hip/hip_runtime.h>

#define N_NODES 100000
#define N_EDGES 1600000
#define N_TOT   (N_NODES + N_EDGES)   // edges + self-loops

// ---------------- CSR build ----------------

__global__ void k_init_deg(int* __restrict__ deg) {
    int i = blockIdx.x * blockDim.x + threadIdx.x;
    if (i < N_NODES) deg[i] = 1;            // self-loop
}

__global__ void k_hist(const int* __restrict__ dst, int* __restrict__ deg) {
    int e = blockIdx.x * blockDim.x + threadIdx.x;
    if (e < N_EDGES) atomicAdd(&deg[dst[e]], 1);
}

__global__ void k_dis(const int* __restrict__ deg, float* __restrict__ dis) {
    int i = blockIdx.x * blockDim.x + threadIdx.x;
    if (i < N_NODES) dis[i] = rsqrtf((float)deg[i]);   // deg >= 1 always
}

// exclusive scan of deg[N] -> rp[N] (block-local), bsums[b] = block total
__global__ void k_scan1(const int* __restrict__ deg, int* __restrict__ rp,
                        int* __restrict__ bsums) {
    __shared__ int sd[256];
    const int t = threadIdx.x, b = blockIdx.x;
    const int base = b * 4096 + t * 16;
    int v[16];
    int s = 0;
    #pragma unroll
    for (int j = 0; j < 16; ++j) {
        int idx = base + j;
        v[j] = (idx < N_NODES) ? deg[idx] : 0;
        s += v[j];
    }
    sd[t] = s;
    __syncthreads();
    const int mine = s;
    for (int off = 1; off < 256; off <<= 1) {
        int x = (t >= off) ? sd[t - off] : 0;
        __syncthreads();
        sd[t] += x;
        __syncthreads();
    }
    int run = sd[t] - mine;   // exclusive prefix of this thread's chunk
    #pragma unroll
    for (int j = 0; j < 16; ++j) {
        int idx = base + j;
        if (idx < N_NODES) rp[idx] = run;
        run += v[j];
    }
    if (t == 255) bsums[b] = sd[255];
}

__global__ void k_scan2(int* __restrict__ bsums, int nb) {
    if (blockIdx.x == 0 && threadIdx.x == 0) {
        int run = 0;
        for (int i = 0; i < nb; ++i) { int x = bsums[i]; bsums[i] = run; run += x; }
    }
}

__global__ void k_scan3(int* __restrict__ rp, const int* __restrict__ bsums) {
    int i = blockIdx.x * blockDim.x + threadIdx.x;
    if (i < N_NODES) rp[i] += bsums[i >> 12];
    if (i == 0) rp[N_NODES] = N_TOT;
}

__global__ void k_setcur(const int* __restrict__ rp, int* __restrict__ cur) {
    int i = blockIdx.x * blockDim.x + threadIdx.x;
    if (i < N_NODES) cur[i] = rp[i];
}

__global__ void k_fill(const int* __restrict__ src, const int* __restrict__ dst,
                       const float* __restrict__ dis, int* __restrict__ cur,
                       int2* __restrict__ ews) {
    int e = blockIdx.x * blockDim.x + threadIdx.x;
    if (e >= N_TOT) return;
    int s, d;
    if (e < N_EDGES) { s = src[e]; d = dst[e]; }
    else             { s = d = e - N_EDGES; }       // self-loop
    int p = atomicAdd(&cur[d], 1);
    float w = dis[s] * dis[d];
    ews[p] = make_int2(s, __float_as_int(w));
}

// ---------------- fp32 GEMM: C[N x DOUT] = A[N x K] @ W[K x DOUT] ----------------
// 128x(DOUT) tile per block, 256 threads, 8xTN per thread, BK=16 LDS-staged.

template <int K, int DOUT, int TN>
__global__ __launch_bounds__(256) void k_gemm(const float* __restrict__ A,
                                              const float* __restrict__ W,
                                              float* __restrict__ C) {
    constexpr int BK = 16;
    __shared__ float As[BK][132];          // k-major, padded
    __shared__ float Ws[BK][DOUT + 4];
    const int tid = threadIdx.x;
    const int tx = tid & 15, ty = tid >> 4;
    const int r0 = blockIdx.x * 128;

    float acc[8][TN];
    #pragma unroll
    for (int i = 0; i < 8; ++i)
        #pragma unroll
        for (int j = 0; j < TN; ++j) acc[i][j] = 0.f;

    for (int k0 = 0; k0 < K; k0 += BK) {
        // A tile: 128 rows x 16 k, transposed into As[k][row]
        #pragma unroll
        for (int l = tid; l < 128 * (BK / 4); l += 256) {
            int row = l / (BK / 4);
            int kc  = (l % (BK / 4)) * 4;
            int gr  = r0 + row;
            float4 a = make_float4(0.f, 0.f, 0.f, 0.f);
            if (gr < N_NODES)
                a = *reinterpret_cast<const float4*>(&A[(size_t)gr * K + k0 + kc]);
            As[kc + 0][row] = a.x; As[kc + 1][row] = a.y;
            As[kc + 2][row] = a.z; As[kc + 3][row] = a.w;
        }
        // W tile: 16 k x DOUT
        #pragma unroll
        for (int l = tid; l < BK * (DOUT / 4); l += 256) {
            int kr = l / (DOUT / 4);
            int c  = (l % (DOUT / 4)) * 4;
            *reinterpret_cast<float4*>(&Ws[kr][c]) =
                *reinterpret_cast<const float4*>(&W[(size_t)(k0 + kr) * DOUT + c]);
        }
        __syncthreads();
        #pragma unroll
        for (int kk = 0; kk < BK; ++kk) {
            float a[8], w[TN];
            #pragma unroll
            for (int i = 0; i < 8; ++i) a[i] = As[kk][ty * 8 + i];
            #pragma unroll
            for (int j = 0; j < TN; ++j) w[j] = Ws[kk][tx * TN + j];
            #pragma unroll
            for (int i = 0; i < 8; ++i)
                #pragma unroll
                for (int j = 0; j < TN; ++j)
                    acc[i][j] = fmaf(a[i], w[j], acc[i][j]);
        }
        __syncthreads();
    }

    #pragma unroll
    for (int i = 0; i < 8; ++i) {
        int gr = r0 + ty * 8 + i;
        if (gr < N_NODES) {
            #pragma unroll
            for (int j = 0; j < TN; j += 4) {
                *reinterpret_cast<float4*>(&C[(size_t)gr * DOUT + tx * TN + j]) =
                    make_float4(acc[i][j], acc[i][j + 1], acc[i][j + 2], acc[i][j + 3]);
            }
        }
    }
}

// ---------------- aggregation: wave per node, fused bias/relu/smooth ----------------

// MODE 0: h = relu(agg + b)           (encoder)
// MODE 1: h = 0.7*h + 0.3*relu(agg+b) (GC iterations)
template <int MODE>
__global__ __launch_bounds__(256) void k_agg128(const float* __restrict__ t,
                                                const int* __restrict__ rp,
                                                const int2* __restrict__ ews,
                                                const float* __restrict__ bias,
                                                float* __restrict__ h) {
    int g = blockIdx.x * 256 + threadIdx.x;
    int node = g >> 6;
    if (node >= N_NODES) return;
    int lane = threadIdx.x & 63;
    int e0 = rp[node], e1 = rp[node + 1];
    float ax = 0.f, ay = 0.f;
    for (int e = e0; e < e1; ++e) {
        int2 ew = ews[e];
        float w = __int_as_float(ew.y);
        float2 v = *reinterpret_cast<const float2*>(&t[(size_t)ew.x * 128 + lane * 2]);
        ax = fmaf(w, v.x, ax);
        ay = fmaf(w, v.y, ay);
    }
    ax += bias[lane * 2];
    ay += bias[lane * 2 + 1];
    float2* hp = reinterpret_cast<float2*>(&h[(size_t)node * 128 + lane * 2]);
    if (MODE == 0) {
        *hp = make_float2(fmaxf(ax, 0.f), fmaxf(ay, 0.f));
    } else {
        float2 old = *hp;
        *hp = make_float2(fmaf(0.7f, old.x, 0.3f * fmaxf(ax, 0.f)),
                          fmaf(0.7f, old.y, 0.3f * fmaxf(ay, 0.f)));
    }
}

// decoder: out = agg + b (64 features, 1 per lane)
__global__ __launch_bounds__(256) void k_agg64(const float* __restrict__ t,
                                               const int* __restrict__ rp,
                                               const int2* __restrict__ ews,
                                               const float* __restrict__ bias,
                                               float* __restrict__ out) {
    int g = blockIdx.x * 256 + threadIdx.x;
    int node = g >> 6;
    if (node >= N_NODES) return;
    int lane = threadIdx.x & 63;
    int e0 = rp[node], e1 = rp[node + 1];
    float a = 0.f;
    for (int e = e0; e < e1; ++e) {
        int2 ew = ews[e];
        a = fmaf(__int_as_float(ew.y), t[(size_t)ew.x * 64 + lane], a);
    }
    out[(size_t)node * 64 + lane] = a + bias[lane];
}

// ---------------- host ----------------

extern "C" void kernel_launch(void* const* d_in, const int* in_sizes, int n_in,
                              void* d_out, int out_size, void* d_ws, size_t ws_size,
                              hipStream_t stream) {
    const float* x     = (const float*)d_in[0];
    const int*   ei    = (const int*)d_in[1];
    const float* W_enc = (const float*)d_in[2];
    const float* b_enc = (const float*)d_in[3];
    const float* W_gc  = (const float*)d_in[4];
    const float* b_gc  = (const float*)d_in[5];
    const float* W_dec = (const float*)d_in[6];
    const float* b_dec = (const float*)d_in[7];
    float* out = (float*)d_out;

    const int* srcp = ei;
    const int* dstp = ei + N_EDGES;

    char* ws = (char*)d_ws;
    size_t off = 0;
    auto take = [&](size_t bytes) -> char* {
        char* p = ws + off;
        off = (off + bytes + 511) & ~(size_t)511;
        return p;
    };
    float* dis  = (float*)take((size_t)N_NODES * 4);
    int*   rp   = (int*)  take((size_t)(N_NODES + 1) * 4);
    int*   cur  = (int*)  take((size_t)N_NODES * 4);
    int*   bs   = (int*)  take(32 * 4);
    int2*  ews  = (int2*) take((size_t)N_TOT * 8);
    float* tbuf = (float*)take((size_t)N_NODES * 128 * 4);
    float* hbuf = (float*)take((size_t)N_NODES * 128 * 4);

    dim3 blk(256);
    int gN = (N_NODES + 255) / 256;
    int gE = (N_EDGES + 255) / 256;
    int gT = (N_TOT + 255) / 256;

    // CSR build (per call — d_ws is re-poisoned before every launch)
    k_init_deg<<<gN, blk, 0, stream>>>(cur);
    k_hist<<<gE, blk, 0, stream>>>(dstp, cur);
    k_dis<<<gN, blk, 0, stream>>>(cur, dis);
    k_scan1<<<25, blk, 0, stream>>>(cur, rp, bs);
    k_scan2<<<1, 64, 0, stream>>>(bs, 25);
    k_scan3<<<gN, blk, 0, stream>>>(rp, bs);
    k_setcur<<<gN, blk, 0, stream>>>(rp, cur);
    k_fill<<<gT, blk, 0, stream>>>(srcp, dstp, dis, cur, ews);

    int gemmG = (N_NODES + 127) / 128;
    int aggG  = (N_NODES * 64 + 255) / 256;

    // encoder: h = relu(agg(x @ W_enc) + b_enc)
    k_gemm<256, 128, 8><<<gemmG, blk, 0, stream>>>(x, W_enc, tbuf);
    k_agg128<0><<<aggG, blk, 0, stream>>>(tbuf, rp, ews, b_enc, hbuf);

    // 8 smoothing iterations: h = 0.7h + 0.3 relu(agg(h @ W_gc) + b_gc)
    for (int it = 0; it < 8; ++it) {
        k_gemm<128, 128, 8><<<gemmG, blk, 0, stream>>>(hbuf, W_gc, tbuf);
        k_agg128<1><<<aggG, blk, 0, stream>>>(tbuf, rp, ews, b_gc, hbuf);
    }

    // decoder: out = agg(h @ W_dec) + b_dec
    k_gemm<128, 64, 4><<<gemmG, blk, 0, stream>>>(hbuf, W_dec, tbuf);
    k_agg64<<<aggG, blk, 0, stream>>>(tbuf, rp, ews, b_dec, out);
}

// Round 2
// 1915.428 us; speedup vs baseline: 1.3701x; 1.3701x over previous
//
#include <hip/hip_runtime.h>
#include <hip/hip_fp16.h>

#define N_NODES 100000
#define N_EDGES 1600000
#define N_TOT   (N_NODES + N_EDGES)   // edges + self-loops

// ---------------- CSR build ----------------

__global__ void k_hist(const int* __restrict__ dst, int* __restrict__ deg) {
    int e = blockIdx.x * blockDim.x + threadIdx.x;
    if (e < N_EDGES) atomicAdd(&deg[dst[e]], 1);
}

__global__ void k_init_deg(int* __restrict__ deg) {
    int i = blockIdx.x * blockDim.x + threadIdx.x;
    if (i < N_NODES) deg[i] = 1;            // self-loop
}

__global__ void k_dis(const int* __restrict__ deg, float* __restrict__ dis) {
    int i = blockIdx.x * blockDim.x + threadIdx.x;
    if (i < N_NODES) dis[i] = rsqrtf((float)deg[i]);   // deg >= 1 always
}

// exclusive scan of deg[N] -> rp[N] (block-local), bsums[b] = block total
__global__ void k_scan1(const int* __restrict__ deg, int* __restrict__ rp,
                        int* __restrict__ bsums) {
    __shared__ int sd[256];
    const int t = threadIdx.x, b = blockIdx.x;
    const int base = b * 4096 + t * 16;
    int v[16];
    int s = 0;
    #pragma unroll
    for (int j = 0; j < 16; ++j) {
        int idx = base + j;
        v[j] = (idx < N_NODES) ? deg[idx] : 0;
        s += v[j];
    }
    sd[t] = s;
    __syncthreads();
    const int mine = s;
    for (int off = 1; off < 256; off <<= 1) {
        int x = (t >= off) ? sd[t - off] : 0;
        __syncthreads();
        sd[t] += x;
        __syncthreads();
    }
    int run = sd[t] - mine;   // exclusive prefix of this thread's chunk
    #pragma unroll
    for (int j = 0; j < 16; ++j) {
        int idx = base + j;
        if (idx < N_NODES) rp[idx] = run;
        run += v[j];
    }
    if (t == 255) bsums[b] = sd[255];
}

__global__ void k_scan2(int* __restrict__ bsums, int nb) {
    if (blockIdx.x == 0 && threadIdx.x == 0) {
        int run = 0;
        for (int i = 0; i < nb; ++i) { int x = bsums[i]; bsums[i] = run; run += x; }
    }
}

__global__ void k_scan3(int* __restrict__ rp, const int* __restrict__ bsums) {
    int i = blockIdx.x * blockDim.x + threadIdx.x;
    if (i < N_NODES) rp[i] += bsums[i >> 12];
    if (i == 0) rp[N_NODES] = N_TOT;
}

__global__ void k_setcur(const int* __restrict__ rp, int* __restrict__ cur) {
    int i = blockIdx.x * blockDim.x + threadIdx.x;
    if (i < N_NODES) cur[i] = rp[i];
}

__global__ void k_fill(const int* __restrict__ src, const int* __restrict__ dst,
                       const float* __restrict__ dis, int* __restrict__ cur,
                       int2* __restrict__ ews) {
    int e = blockIdx.x * blockDim.x + threadIdx.x;
    if (e >= N_TOT) return;
    int s, d;
    if (e < N_EDGES) { s = src[e]; d = dst[e]; }
    else             { s = d = e - N_EDGES; }       // self-loop
    int p = atomicAdd(&cur[d], 1);
    float w = dis[s] * dis[d];
    ews[p] = make_int2(s, __float_as_int(w));
}

// ---------------- fp32 GEMM: C[N x DOUT] = A[N x K] @ W[K x DOUT] ----------------
// 128x(DOUT) tile per block, 256 threads, 8xTN per thread, BK=16 LDS-staged.
// HALF_OUT: store C as fp16 (consumed only by the gather-aggregate).

template <int K, int DOUT, int TN, bool HALF_OUT>
__global__ __launch_bounds__(256) void k_gemm(const float* __restrict__ A,
                                              const float* __restrict__ W,
                                              void* __restrict__ Cv) {
    constexpr int BK = 16;
    __shared__ float As[BK][132];          // k-major, padded
    __shared__ float Ws[BK][DOUT + 4];
    const int tid = threadIdx.x;
    const int tx = tid & 15, ty = tid >> 4;
    const int r0 = blockIdx.x * 128;

    float acc[8][TN];
    #pragma unroll
    for (int i = 0; i < 8; ++i)
        #pragma unroll
        for (int j = 0; j < TN; ++j) acc[i][j] = 0.f;

    for (int k0 = 0; k0 < K; k0 += BK) {
        // A tile: 128 rows x 16 k, transposed into As[k][row]
        #pragma unroll
        for (int l = tid; l < 128 * (BK / 4); l += 256) {
            int row = l / (BK / 4);
            int kc  = (l % (BK / 4)) * 4;
            int gr  = r0 + row;
            float4 a = make_float4(0.f, 0.f, 0.f, 0.f);
            if (gr < N_NODES)
                a = *reinterpret_cast<const float4*>(&A[(size_t)gr * K + k0 + kc]);
            As[kc + 0][row] = a.x; As[kc + 1][row] = a.y;
            As[kc + 2][row] = a.z; As[kc + 3][row] = a.w;
        }
        // W tile: 16 k x DOUT
        #pragma unroll
        for (int l = tid; l < BK * (DOUT / 4); l += 256) {
            int kr = l / (DOUT / 4);
            int c  = (l % (DOUT / 4)) * 4;
            *reinterpret_cast<float4*>(&Ws[kr][c]) =
                *reinterpret_cast<const float4*>(&W[(size_t)(k0 + kr) * DOUT + c]);
        }
        __syncthreads();
        #pragma unroll
        for (int kk = 0; kk < BK; ++kk) {
            float a[8], w[TN];
            #pragma unroll
            for (int i = 0; i < 8; ++i) a[i] = As[kk][ty * 8 + i];
            #pragma unroll
            for (int j = 0; j < TN; ++j) w[j] = Ws[kk][tx * TN + j];
            #pragma unroll
            for (int i = 0; i < 8; ++i)
                #pragma unroll
                for (int j = 0; j < TN; ++j)
                    acc[i][j] = fmaf(a[i], w[j], acc[i][j]);
        }
        __syncthreads();
    }

    #pragma unroll
    for (int i = 0; i < 8; ++i) {
        int gr = r0 + ty * 8 + i;
        if (gr >= N_NODES) continue;
        if constexpr (HALF_OUT) {
            __half* Ch = (__half*)Cv;
            union { int4 i4; __half2 h2[4]; } u;
            #pragma unroll
            for (int j = 0; j < TN; j += 2)
                u.h2[j / 2] = __floats2half2_rn(acc[i][j], acc[i][j + 1]);
            static_assert(TN == 8, "half path assumes TN==8");
            *reinterpret_cast<int4*>(&Ch[(size_t)gr * DOUT + tx * TN]) = u.i4;
        } else {
            float* C = (float*)Cv;
            #pragma unroll
            for (int j = 0; j < TN; j += 4) {
                *reinterpret_cast<float4*>(&C[(size_t)gr * DOUT + tx * TN + j]) =
                    make_float4(acc[i][j], acc[i][j + 1], acc[i][j + 2], acc[i][j + 3]);
            }
        }
    }
}

// ---------------- aggregation: wave per node, fused bias/relu/smooth ----------------
// t is fp16 [N x 128]; accumulate fp32; h stays fp32.
// MODE 0: h = relu(agg + b)           (encoder)
// MODE 1: h = 0.7*h + 0.3*relu(agg+b) (GC iterations)
template <int MODE>
__global__ __launch_bounds__(256) void k_agg128h(const __half* __restrict__ t,
                                                 const int* __restrict__ rp,
                                                 const int2* __restrict__ ews,
                                                 const float* __restrict__ bias,
                                                 float* __restrict__ h) {
    int g = blockIdx.x * 256 + threadIdx.x;
    int node = g >> 6;
    if (node >= N_NODES) return;
    int lane = threadIdx.x & 63;
    int e0 = rp[node], e1 = rp[node + 1];
    float ax = 0.f, ay = 0.f;
    int e = e0;
    for (; e + 1 < e1; e += 2) {
        int2 ew0 = ews[e];
        int2 ew1 = ews[e + 1];
        __half2 v0 = *reinterpret_cast<const __half2*>(&t[(size_t)ew0.x * 128 + lane * 2]);
        __half2 v1 = *reinterpret_cast<const __half2*>(&t[(size_t)ew1.x * 128 + lane * 2]);
        float w0 = __int_as_float(ew0.y);
        float w1 = __int_as_float(ew1.y);
        float2 f0 = __half22float2(v0);
        float2 f1 = __half22float2(v1);
        ax = fmaf(w0, f0.x, ax); ay = fmaf(w0, f0.y, ay);
        ax = fmaf(w1, f1.x, ax); ay = fmaf(w1, f1.y, ay);
    }
    if (e < e1) {
        int2 ew = ews[e];
        __half2 v = *reinterpret_cast<const __half2*>(&t[(size_t)ew.x * 128 + lane * 2]);
        float w = __int_as_float(ew.y);
        float2 f = __half22float2(v);
        ax = fmaf(w, f.x, ax); ay = fmaf(w, f.y, ay);
    }
    ax += bias[lane * 2];
    ay += bias[lane * 2 + 1];
    float2* hp = reinterpret_cast<float2*>(&h[(size_t)node * 128 + lane * 2]);
    if (MODE == 0) {
        *hp = make_float2(fmaxf(ax, 0.f), fmaxf(ay, 0.f));
    } else {
        float2 old = *hp;
        *hp = make_float2(fmaf(0.7f, old.x, 0.3f * fmaxf(ax, 0.f)),
                          fmaf(0.7f, old.y, 0.3f * fmaxf(ay, 0.f)));
    }
}

// decoder: out = agg + b (64 features, 1 per lane). fp32 t (error hits output undamped).
__global__ __launch_bounds__(256) void k_agg64(const float* __restrict__ t,
                                               const int* __restrict__ rp,
                                               const int2* __restrict__ ews,
                                               const float* __restrict__ bias,
                                               float* __restrict__ out) {
    int g = blockIdx.x * 256 + threadIdx.x;
    int node = g >> 6;
    if (node >= N_NODES) return;
    int lane = threadIdx.x & 63;
    int e0 = rp[node], e1 = rp[node + 1];
    float a = 0.f;
    int e = e0;
    for (; e + 1 < e1; e += 2) {
        int2 ew0 = ews[e];
        int2 ew1 = ews[e + 1];
        float v0 = t[(size_t)ew0.x * 64 + lane];
        float v1 = t[(size_t)ew1.x * 64 + lane];
        a = fmaf(__int_as_float(ew0.y), v0, a);
        a = fmaf(__int_as_float(ew1.y), v1, a);
    }
    if (e < e1) {
        int2 ew = ews[e];
        a = fmaf(__int_as_float(ew.y), t[(size_t)ew.x * 64 + lane], a);
    }
    out[(size_t)node * 64 + lane] = a + bias[lane];
}

// ---------------- host ----------------

extern "C" void kernel_launch(void* const* d_in, const int* in_sizes, int n_in,
                              void* d_out, int out_size, void* d_ws, size_t ws_size,
                              hipStream_t stream) {
    const float* x     = (const float*)d_in[0];
    const int*   ei    = (const int*)d_in[1];
    const float* W_enc = (const float*)d_in[2];
    const float* b_enc = (const float*)d_in[3];
    const float* W_gc  = (const float*)d_in[4];
    const float* b_gc  = (const float*)d_in[5];
    const float* W_dec = (const float*)d_in[6];
    const float* b_dec = (const float*)d_in[7];
    float* out = (float*)d_out;

    const int* srcp = ei;
    const int* dstp = ei + N_EDGES;

    char* ws = (char*)d_ws;
    size_t off = 0;
    auto take = [&](size_t bytes) -> char* {
        char* p = ws + off;
        off = (off + bytes + 511) & ~(size_t)511;
        return p;
    };
    float*  dis  = (float*) take((size_t)N_NODES * 4);
    int*    rp   = (int*)   take((size_t)(N_NODES + 1) * 4);
    int*    cur  = (int*)   take((size_t)N_NODES * 4);
    int*    bs   = (int*)   take(32 * 4);
    int2*   ews  = (int2*)  take((size_t)N_TOT * 8);
    __half* th   = (__half*)take((size_t)N_NODES * 128 * 2);  // fp16 transform buffer
    float*  td   = (float*) take((size_t)N_NODES * 64 * 4);   // fp32 decoder transform
    float*  hbuf = (float*) take((size_t)N_NODES * 128 * 4);

    dim3 blk(256);
    int gN = (N_NODES + 255) / 256;
    int gE = (N_EDGES + 255) / 256;
    int gT = (N_TOT + 255) / 256;

    // CSR build (per call — d_ws is re-poisoned before every launch)
    k_init_deg<<<gN, blk, 0, stream>>>(cur);
    k_hist<<<gE, blk, 0, stream>>>(dstp, cur);
    k_dis<<<gN, blk, 0, stream>>>(cur, dis);
    k_scan1<<<25, blk, 0, stream>>>(cur, rp, bs);
    k_scan2<<<1, 64, 0, stream>>>(bs, 25);
    k_scan3<<<gN, blk, 0, stream>>>(rp, bs);
    k_setcur<<<gN, blk, 0, stream>>>(rp, cur);
    k_fill<<<gT, blk, 0, stream>>>(srcp, dstp, dis, cur, ews);

    int gemmG = (N_NODES + 127) / 128;
    int aggG  = (N_NODES * 64 + 255) / 256;

    // encoder: h = relu(agg(x @ W_enc) + b_enc)
    k_gemm<256, 128, 8, true><<<gemmG, blk, 0, stream>>>(x, W_enc, th);
    k_agg128h<0><<<aggG, blk, 0, stream>>>(th, rp, ews, b_enc, hbuf);

    // 8 smoothing iterations: h = 0.7h + 0.3 relu(agg(h @ W_gc) + b_gc)
    for (int it = 0; it < 8; ++it) {
        k_gemm<128, 128, 8, true><<<gemmG, blk, 0, stream>>>(hbuf, W_gc, th);
        k_agg128h<1><<<aggG, blk, 0, stream>>>(th, rp, ews, b_gc, hbuf);
    }

    // decoder: out = agg(h @ W_dec) + b_dec  (fp32 path — undamped error)
    k_gemm<128, 64, 4, false><<<gemmG, blk, 0, stream>>>(hbuf, W_dec, td);
    k_agg64<<<aggG, blk, 0, stream>>>(td, rp, ews, b_dec, out);
}

// Round 3
// 1580.112 us; speedup vs baseline: 1.6608x; 1.2122x over previous
//
#include <hip/hip_runtime.h>
#include <hip/hip_fp16.h>

#define N_NODES 100000
#define N_EDGES 1600000
#define N_TOT   (N_NODES + N_EDGES)   // edges + self-loops

typedef __attribute__((ext_vector_type(8))) _Float16 f16x8;
typedef __attribute__((ext_vector_type(4))) float    f32x4;

// ---------------- CSR build ----------------

__global__ void k_hist(const int* __restrict__ dst, int* __restrict__ deg) {
    int e = blockIdx.x * blockDim.x + threadIdx.x;
    if (e < N_EDGES) atomicAdd(&deg[dst[e]], 1);
}

__global__ void k_init_deg(int* __restrict__ deg) {
    int i = blockIdx.x * blockDim.x + threadIdx.x;
    if (i < N_NODES) deg[i] = 1;            // self-loop
}

__global__ void k_dis(const int* __restrict__ deg, float* __restrict__ dis) {
    int i = blockIdx.x * blockDim.x + threadIdx.x;
    if (i < N_NODES) dis[i] = rsqrtf((float)deg[i]);   // deg >= 1 always
}

// exclusive scan of deg[N] -> rp[N] (block-local), bsums[b] = block total
__global__ void k_scan1(const int* __restrict__ deg, int* __restrict__ rp,
                        int* __restrict__ bsums) {
    __shared__ int sd[256];
    const int t = threadIdx.x, b = blockIdx.x;
    const int base = b * 4096 + t * 16;
    int v[16];
    int s = 0;
    #pragma unroll
    for (int j = 0; j < 16; ++j) {
        int idx = base + j;
        v[j] = (idx < N_NODES) ? deg[idx] : 0;
        s += v[j];
    }
    sd[t] = s;
    __syncthreads();
    const int mine = s;
    for (int off = 1; off < 256; off <<= 1) {
        int x = (t >= off) ? sd[t - off] : 0;
        __syncthreads();
        sd[t] += x;
        __syncthreads();
    }
    int run = sd[t] - mine;   // exclusive prefix of this thread's chunk
    #pragma unroll
    for (int j = 0; j < 16; ++j) {
        int idx = base + j;
        if (idx < N_NODES) rp[idx] = run;
        run += v[j];
    }
    if (t == 255) bsums[b] = sd[255];
}

__global__ void k_scan2(int* __restrict__ bsums, int nb) {
    if (blockIdx.x == 0 && threadIdx.x == 0) {
        int run = 0;
        for (int i = 0; i < nb; ++i) { int x = bsums[i]; bsums[i] = run; run += x; }
    }
}

__global__ void k_scan3(int* __restrict__ rp, const int* __restrict__ bsums) {
    int i = blockIdx.x * blockDim.x + threadIdx.x;
    if (i < N_NODES) rp[i] += bsums[i >> 12];
    if (i == 0) rp[N_NODES] = N_TOT;
}

__global__ void k_setcur(const int* __restrict__ rp, int* __restrict__ cur) {
    int i = blockIdx.x * blockDim.x + threadIdx.x;
    if (i < N_NODES) cur[i] = rp[i];
}

__global__ void k_fill(const int* __restrict__ src, const int* __restrict__ dst,
                       const float* __restrict__ dis, int* __restrict__ cur,
                       int2* __restrict__ ews) {
    int e = blockIdx.x * blockDim.x + threadIdx.x;
    if (e >= N_TOT) return;
    int s, d;
    if (e < N_EDGES) { s = src[e]; d = dst[e]; }
    else             { s = d = e - N_EDGES; }       // self-loop
    int p = atomicAdd(&cur[d], 1);
    float w = dis[s] * dis[d];
    ews[p] = make_int2(s, __float_as_int(w));
}

// ---------------- MFMA GEMM: C[N x DOUT](fp16) = A[N x K](fp32) @ W[K x DOUT](fp32) ----------------
// 256 thr / 4 waves; wave = 16-row strip. W chunk staged col-major in LDS (pad +8 halfs).
// Operand-swapped mfma: D = W^T * A^T piecewise -> lane&15 = node row, 4 regs = 4 consecutive cols.

template <int K, int DOUT>
__global__ __launch_bounds__(256) void k_gemm_mfma(const float* __restrict__ A,
                                                   const float* __restrict__ W,
                                                   __half* __restrict__ C) {
    constexpr int KC  = 128;
    constexpr int LDK = KC + 8;           // 136 halfs = 272 B row stride (col-major)
    constexpr int NCT = DOUT / 16;
    __shared__ _Float16 Wlds[DOUT * LDK];

    const int tid = threadIdx.x;
    const int w   = tid >> 6, l = tid & 63;
    const int l15 = l & 15,  g = l >> 4;          // g in 0..3
    const int row  = blockIdx.x * 64 + w * 16 + l15;
    const int rowc = row < N_NODES ? row : N_NODES - 1;

    f32x4 acc[NCT];
    #pragma unroll
    for (int ct = 0; ct < NCT; ++ct) acc[ct] = (f32x4)(0.f);

    for (int k0 = 0; k0 < K; k0 += KC) {
        if (k0) __syncthreads();
        // stage W[k0+kk][col] -> Wlds[col*LDK + kk] (fp16, col-major)
        constexpr int ITEMS = DOUT * (KC / 8);
        #pragma unroll
        for (int item = tid; item < ITEMS; item += 256) {
            int col = item % DOUT;
            int kk  = (item / DOUT) * 8;
            f16x8 v;
            #pragma unroll
            for (int u = 0; u < 8; ++u)
                v[u] = (_Float16)W[(size_t)(k0 + kk + u) * DOUT + col];
            *reinterpret_cast<f16x8*>(&Wlds[col * LDK + kk]) = v;
        }
        __syncthreads();

        #pragma unroll
        for (int ks = 0; ks < KC; ks += 32) {
            const float* ap = &A[(size_t)rowc * K + k0 + ks + g * 8];
            float4 a0 = *reinterpret_cast<const float4*>(ap);
            float4 a1 = *reinterpret_cast<const float4*>(ap + 4);
            f16x8 af;
            af[0] = (_Float16)a0.x; af[1] = (_Float16)a0.y;
            af[2] = (_Float16)a0.z; af[3] = (_Float16)a0.w;
            af[4] = (_Float16)a1.x; af[5] = (_Float16)a1.y;
            af[6] = (_Float16)a1.z; af[7] = (_Float16)a1.w;
            #pragma unroll
            for (int ct = 0; ct < NCT; ++ct) {
                f16x8 wf = *reinterpret_cast<const f16x8*>(
                    &Wlds[(ct * 16 + l15) * LDK + ks + g * 8]);
                acc[ct] = __builtin_amdgcn_mfma_f32_16x16x32_f16(wf, af, acc[ct], 0, 0, 0);
            }
        }
    }

    if (row < N_NODES) {
        #pragma unroll
        for (int ct = 0; ct < NCT; ++ct) {
            union { uint2 u; __half2 h[2]; } s;
            s.h[0] = __floats2half2_rn(acc[ct][0], acc[ct][1]);
            s.h[1] = __floats2half2_rn(acc[ct][2], acc[ct][3]);
            *reinterpret_cast<uint2*>(&C[(size_t)row * DOUT + ct * 16 + g * 4]) = s.u;
        }
    }
}

// ---------------- aggregation: wave per node, fused bias/relu/smooth ----------------
// t is fp16 [N x 128]; accumulate fp32; h stays fp32.
// MODE 0: h = relu(agg + b)           (encoder)
// MODE 1: h = 0.7*h + 0.3*relu(agg+b) (GC iterations)
template <int MODE>
__global__ __launch_bounds__(256) void k_agg128h(const __half* __restrict__ t,
                                                 const int* __restrict__ rp,
                                                 const int2* __restrict__ ews,
                                                 const float* __restrict__ bias,
                                                 float* __restrict__ h) {
    int g = blockIdx.x * 256 + threadIdx.x;
    int node = g >> 6;
    if (node >= N_NODES) return;
    int lane = threadIdx.x & 63;
    int e0 = rp[node], e1 = rp[node + 1];
    float ax = 0.f, ay = 0.f;
    int e = e0;
    for (; e + 1 < e1; e += 2) {
        int2 ew0 = ews[e];
        int2 ew1 = ews[e + 1];
        __half2 v0 = *reinterpret_cast<const __half2*>(&t[(size_t)ew0.x * 128 + lane * 2]);
        __half2 v1 = *reinterpret_cast<const __half2*>(&t[(size_t)ew1.x * 128 + lane * 2]);
        float w0 = __int_as_float(ew0.y);
        float w1 = __int_as_float(ew1.y);
        float2 f0 = __half22float2(v0);
        float2 f1 = __half22float2(v1);
        ax = fmaf(w0, f0.x, ax); ay = fmaf(w0, f0.y, ay);
        ax = fmaf(w1, f1.x, ax); ay = fmaf(w1, f1.y, ay);
    }
    if (e < e1) {
        int2 ew = ews[e];
        __half2 v = *reinterpret_cast<const __half2*>(&t[(size_t)ew.x * 128 + lane * 2]);
        float w = __int_as_float(ew.y);
        float2 f = __half22float2(v);
        ax = fmaf(w, f.x, ax); ay = fmaf(w, f.y, ay);
    }
    ax += bias[lane * 2];
    ay += bias[lane * 2 + 1];
    float2* hp = reinterpret_cast<float2*>(&h[(size_t)node * 128 + lane * 2]);
    if (MODE == 0) {
        *hp = make_float2(fmaxf(ax, 0.f), fmaxf(ay, 0.f));
    } else {
        float2 old = *hp;
        *hp = make_float2(fmaf(0.7f, old.x, 0.3f * fmaxf(ax, 0.f)),
                          fmaf(0.7f, old.y, 0.3f * fmaxf(ay, 0.f)));
    }
}

// decoder: out = agg + b (64 features, 1 per lane). fp16 t, fp32 accumulate.
__global__ __launch_bounds__(256) void k_agg64h(const __half* __restrict__ t,
                                                const int* __restrict__ rp,
                                                const int2* __restrict__ ews,
                                                const float* __restrict__ bias,
                                                float* __restrict__ out) {
    int g = blockIdx.x * 256 + threadIdx.x;
    int node = g >> 6;
    if (node >= N_NODES) return;
    int lane = threadIdx.x & 63;
    int e0 = rp[node], e1 = rp[node + 1];
    float a = 0.f;
    int e = e0;
    for (; e + 1 < e1; e += 2) {
        int2 ew0 = ews[e];
        int2 ew1 = ews[e + 1];
        float v0 = __half2float(t[(size_t)ew0.x * 64 + lane]);
        float v1 = __half2float(t[(size_t)ew1.x * 64 + lane]);
        a = fmaf(__int_as_float(ew0.y), v0, a);
        a = fmaf(__int_as_float(ew1.y), v1, a);
    }
    if (e < e1) {
        int2 ew = ews[e];
        a = fmaf(__int_as_float(ew.y), __half2float(t[(size_t)ew.x * 64 + lane]), a);
    }
    out[(size_t)node * 64 + lane] = a + bias[lane];
}

// ---------------- host ----------------

extern "C" void kernel_launch(void* const* d_in, const int* in_sizes, int n_in,
                              void* d_out, int out_size, void* d_ws, size_t ws_size,
                              hipStream_t stream) {
    const float* x     = (const float*)d_in[0];
    const int*   ei    = (const int*)d_in[1];
    const float* W_enc = (const float*)d_in[2];
    const float* b_enc = (const float*)d_in[3];
    const float* W_gc  = (const float*)d_in[4];
    const float* b_gc  = (const float*)d_in[5];
    const float* W_dec = (const float*)d_in[6];
    const float* b_dec = (const float*)d_in[7];
    float* out = (float*)d_out;

    const int* srcp = ei;
    const int* dstp = ei + N_EDGES;

    char* ws = (char*)d_ws;
    size_t off = 0;
    auto take = [&](size_t bytes) -> char* {
        char* p = ws + off;
        off = (off + bytes + 511) & ~(size_t)511;
        return p;
    };
    float*  dis  = (float*) take((size_t)N_NODES * 4);
    int*    rp   = (int*)   take((size_t)(N_NODES + 1) * 4);
    int*    cur  = (int*)   take((size_t)N_NODES * 4);
    int*    bs   = (int*)   take(32 * 4);
    int2*   ews  = (int2*)  take((size_t)N_TOT * 8);
    __half* th   = (__half*)take((size_t)N_NODES * 128 * 2);  // fp16 transform buffer
    __half* td   = (__half*)take((size_t)N_NODES * 64 * 2);   // fp16 decoder transform
    float*  hbuf = (float*) take((size_t)N_NODES * 128 * 4);

    dim3 blk(256);
    int gN = (N_NODES + 255) / 256;
    int gE = (N_EDGES + 255) / 256;
    int gT = (N_TOT + 255) / 256;

    // CSR build (per call — d_ws is re-poisoned before every launch)
    k_init_deg<<<gN, blk, 0, stream>>>(cur);
    k_hist<<<gE, blk, 0, stream>>>(dstp, cur);
    k_dis<<<gN, blk, 0, stream>>>(cur, dis);
    k_scan1<<<25, blk, 0, stream>>>(cur, rp, bs);
    k_scan2<<<1, 64, 0, stream>>>(bs, 25);
    k_scan3<<<gN, blk, 0, stream>>>(rp, bs);
    k_setcur<<<gN, blk, 0, stream>>>(rp, cur);
    k_fill<<<gT, blk, 0, stream>>>(srcp, dstp, dis, cur, ews);

    int gemmG = (N_NODES + 63) / 64;
    int aggG  = (N_NODES * 64 + 255) / 256;

    // encoder: h = relu(agg(x @ W_enc) + b_enc)
    k_gemm_mfma<256, 128><<<gemmG, blk, 0, stream>>>(x, W_enc, th);
    k_agg128h<0><<<aggG, blk, 0, stream>>>(th, rp, ews, b_enc, hbuf);

    // 8 smoothing iterations: h = 0.7h + 0.3 relu(agg(h @ W_gc) + b_gc)
    for (int it = 0; it < 8; ++it) {
        k_gemm_mfma<128, 128><<<gemmG, blk, 0, stream>>>(hbuf, W_gc, th);
        k_agg128h<1><<<aggG, blk, 0, stream>>>(th, rp, ews, b_gc, hbuf);
    }

    // decoder: out = agg(h @ W_dec) + b_dec
    k_gemm_mfma<128, 64><<<gemmG, blk, 0, stream>>>(hbuf, W_dec, td);
    k_agg64h<<<aggG, blk, 0, stream>>>(td, rp, ews, b_dec, out);
}

// Round 5
// 1218.742 us; speedup vs baseline: 2.1533x; 1.2965x over previous
//
#include <hip/hip_runtime.h>
#include <hip/hip_fp16.h>

#define N_NODES 100000
#define N_EDGES 1600000
#define N_TOT   (N_NODES + N_EDGES)   // edges + self-loops

typedef __attribute__((ext_vector_type(8))) _Float16 f16x8;
typedef __attribute__((ext_vector_type(4))) _Float16 f16x4;
typedef __attribute__((ext_vector_type(4))) float    f32x4;

// ---------------- CSR build ----------------

__global__ void k_hist(const int* __restrict__ dst, int* __restrict__ deg) {
    int e = blockIdx.x * blockDim.x + threadIdx.x;
    if (e < N_EDGES) atomicAdd(&deg[dst[e]], 1);
}

__global__ void k_init_deg(int* __restrict__ deg) {
    int i = blockIdx.x * blockDim.x + threadIdx.x;
    if (i < N_NODES) deg[i] = 1;            // self-loop
}

__global__ void k_dis(const int* __restrict__ deg, float* __restrict__ dis) {
    int i = blockIdx.x * blockDim.x + threadIdx.x;
    if (i < N_NODES) dis[i] = rsqrtf((float)deg[i]);   // deg >= 1 always
}

// exclusive scan of deg[N] -> rp[N] (block-local), bsums[b] = block total
__global__ void k_scan1(const int* __restrict__ deg, int* __restrict__ rp,
                        int* __restrict__ bsums) {
    __shared__ int sd[256];
    const int t = threadIdx.x, b = blockIdx.x;
    const int base = b * 4096 + t * 16;
    int v[16];
    int s = 0;
    #pragma unroll
    for (int j = 0; j < 16; ++j) {
        int idx = base + j;
        v[j] = (idx < N_NODES) ? deg[idx] : 0;
        s += v[j];
    }
    sd[t] = s;
    __syncthreads();
    const int mine = s;
    for (int off = 1; off < 256; off <<= 1) {
        int x = (t >= off) ? sd[t - off] : 0;
        __syncthreads();
        sd[t] += x;
        __syncthreads();
    }
    int run = sd[t] - mine;   // exclusive prefix of this thread's chunk
    #pragma unroll
    for (int j = 0; j < 16; ++j) {
        int idx = base + j;
        if (idx < N_NODES) rp[idx] = run;
        run += v[j];
    }
    if (t == 255) bsums[b] = sd[255];
}

__global__ void k_scan2(int* __restrict__ bsums, int nb) {
    if (blockIdx.x == 0 && threadIdx.x == 0) {
        int run = 0;
        for (int i = 0; i < nb; ++i) { int x = bsums[i]; bsums[i] = run; run += x; }
    }
}

__global__ void k_scan3(int* __restrict__ rp, const int* __restrict__ bsums) {
    int i = blockIdx.x * blockDim.x + threadIdx.x;
    if (i < N_NODES) rp[i] += bsums[i >> 12];
    if (i == 0) rp[N_NODES] = N_TOT;
}

__global__ void k_setcur(const int* __restrict__ rp, int* __restrict__ cur) {
    int i = blockIdx.x * blockDim.x + threadIdx.x;
    if (i < N_NODES) cur[i] = rp[i];
}

__global__ void k_fill(const int* __restrict__ src, const int* __restrict__ dst,
                       const float* __restrict__ dis, int* __restrict__ cur,
                       int2* __restrict__ ews) {
    int e = blockIdx.x * blockDim.x + threadIdx.x;
    if (e >= N_TOT) return;
    int s, d;
    if (e < N_EDGES) { s = src[e]; d = dst[e]; }
    else             { s = d = e - N_EDGES; }       // self-loop
    int p = atomicAdd(&cur[d], 1);
    float w = dis[s] * dis[d];
    ews[p] = make_int2(s, __float_as_int(w));
}

// ---------------- W pre-convert: W[K x DOUT] fp32 -> Wt[DOUT x K] fp16 ----------------
__global__ void k_wt(const float* __restrict__ W, __half* __restrict__ Wt,
                     int K, int DOUT) {
    int i = blockIdx.x * blockDim.x + threadIdx.x;
    if (i >= K * DOUT) return;
    int k = i % K, c = i / K;
    Wt[(size_t)c * K + k] = __float2half(W[(size_t)k * DOUT + c]);
}

// ---------------- MFMA GEMM: C[N x DOUT](fp16) = A[N x K](fp32) @ W ----------------
// Wt is fp16 col-major [DOUT][K]. 256 thr / 4 waves; wave = 16-row strip.
// Operand-swapped mfma -> lane&15 = node row, 4 acc regs = 4 consecutive cols.

template <int K, int DOUT>
__global__ __launch_bounds__(256) void k_gemm_mfma(const float* __restrict__ A,
                                                   const __half* __restrict__ Wt,
                                                   __half* __restrict__ C) {
    constexpr int KC  = 128;
    constexpr int LDK = KC + 8;           // pad: 2-way LDS aliasing only
    constexpr int NCT = DOUT / 16;
    __shared__ _Float16 Wlds[DOUT * LDK];

    const int tid = threadIdx.x;
    const int w   = tid >> 6, l = tid & 63;
    const int l15 = l & 15,  g = l >> 4;          // g in 0..3
    const int row  = blockIdx.x * 64 + w * 16 + l15;
    const int rowc = row < N_NODES ? row : N_NODES - 1;

    f32x4 acc[NCT];
    #pragma unroll
    for (int ct = 0; ct < NCT; ++ct) acc[ct] = (f32x4)(0.f);

    for (int k0 = 0; k0 < K; k0 += KC) {
        if (k0) __syncthreads();
        // stage Wt[col][k0..k0+KC) -> Wlds[col*LDK + kk], coalesced 16B loads
        constexpr int ITEMS = DOUT * (KC / 8);
        #pragma unroll
        for (int item = tid; item < ITEMS; item += 256) {
            int col = item / (KC / 8);
            int kk  = (item % (KC / 8)) * 8;
            *reinterpret_cast<f16x8*>(&Wlds[col * LDK + kk]) =
                *reinterpret_cast<const f16x8*>(&Wt[(size_t)col * K + k0 + kk]);
        }
        __syncthreads();

        #pragma unroll
        for (int ks = 0; ks < KC; ks += 32) {
            const float* ap = &A[(size_t)rowc * K + k0 + ks + g * 8];
            float4 a0 = *reinterpret_cast<const float4*>(ap);
            float4 a1 = *reinterpret_cast<const float4*>(ap + 4);
            f16x8 af;
            af[0] = (_Float16)a0.x; af[1] = (_Float16)a0.y;
            af[2] = (_Float16)a0.z; af[3] = (_Float16)a0.w;
            af[4] = (_Float16)a1.x; af[5] = (_Float16)a1.y;
            af[6] = (_Float16)a1.z; af[7] = (_Float16)a1.w;
            #pragma unroll
            for (int ct = 0; ct < NCT; ++ct) {
                f16x8 wf = *reinterpret_cast<const f16x8*>(
                    &Wlds[(ct * 16 + l15) * LDK + ks + g * 8]);
                acc[ct] = __builtin_amdgcn_mfma_f32_16x16x32_f16(wf, af, acc[ct], 0, 0, 0);
            }
        }
    }

    if (row < N_NODES) {
        #pragma unroll
        for (int ct = 0; ct < NCT; ++ct) {
            union { uint2 u; __half2 h[2]; } s;
            s.h[0] = __floats2half2_rn(acc[ct][0], acc[ct][1]);
            s.h[1] = __floats2half2_rn(acc[ct][2], acc[ct][3]);
            *reinterpret_cast<uint2*>(&C[(size_t)row * DOUT + ct * 16 + g * 4]) = s.u;
        }
    }
}

// ---------------- aggregation: wave per node, 4 edges per gather instruction ----------------
// quarter q = lane>>4 handles edge e+q; lane reads f16x8 (16B) = 8 features.
// Cross-quarter reduce via shfl_xor; epilogue from quarter 0.
// MODE 0: h = relu(agg + b); MODE 1: h = 0.7*h + 0.3*relu(agg + b)
template <int MODE>
__global__ __launch_bounds__(256) void k_agg128v(const __half* __restrict__ t,
                                                 const int* __restrict__ rp,
                                                 const int2* __restrict__ ews,
                                                 const float* __restrict__ bias,
                                                 float* __restrict__ h) {
    int node = (blockIdx.x * 256 + threadIdx.x) >> 6;
    if (node >= N_NODES) return;
    const int lane = threadIdx.x & 63;
    const int q  = lane >> 4;        // edge slot 0..3
    const int fl = lane & 15;        // feature block (8 features)
    const int e0 = rp[node], e1 = rp[node + 1];

    float acc[8];
    #pragma unroll
    for (int i = 0; i < 8; ++i) acc[i] = 0.f;

    int e = e0;
    for (; e + 7 < e1; e += 8) {
        int2 ewA = ews[e + q];
        int2 ewB = ews[e + 4 + q];
        f16x8 vA = *reinterpret_cast<const f16x8*>(&t[(size_t)ewA.x * 128 + fl * 8]);
        f16x8 vB = *reinterpret_cast<const f16x8*>(&t[(size_t)ewB.x * 128 + fl * 8]);
        float wA = __int_as_float(ewA.y);
        float wB = __int_as_float(ewB.y);
        #pragma unroll
        for (int i = 0; i < 8; ++i) acc[i] = fmaf((float)vA[i], wA, acc[i]);
        #pragma unroll
        for (int i = 0; i < 8; ++i) acc[i] = fmaf((float)vB[i], wB, acc[i]);
    }
    for (; e < e1; e += 4) {
        int idx = e + q;
        bool ok = idx < e1;
        idx = ok ? idx : e1 - 1;
        int2 ew = ews[idx];
        float w = ok ? __int_as_float(ew.y) : 0.f;
        f16x8 v = *reinterpret_cast<const f16x8*>(&t[(size_t)ew.x * 128 + fl * 8]);
        #pragma unroll
        for (int i = 0; i < 8; ++i) acc[i] = fmaf((float)v[i], w, acc[i]);
    }

    #pragma unroll
    for (int i = 0; i < 8; ++i) {
        acc[i] += __shfl_xor(acc[i], 16);
        acc[i] += __shfl_xor(acc[i], 32);
    }

    if (q == 0) {
        float* hp = &h[(size_t)node * 128 + fl * 8];
        const float* bp = &bias[fl * 8];
        #pragma unroll
        for (int i = 0; i < 8; i += 4) {
            float4 b4 = *reinterpret_cast<const float4*>(bp + i);
            float4 r;
            r.x = fmaxf(acc[i + 0] + b4.x, 0.f);
            r.y = fmaxf(acc[i + 1] + b4.y, 0.f);
            r.z = fmaxf(acc[i + 2] + b4.z, 0.f);
            r.w = fmaxf(acc[i + 3] + b4.w, 0.f);
            if (MODE == 1) {
                float4 old = *reinterpret_cast<const float4*>(hp + i);
                r.x = fmaf(0.7f, old.x, 0.3f * r.x);
                r.y = fmaf(0.7f, old.y, 0.3f * r.y);
                r.z = fmaf(0.7f, old.z, 0.3f * r.z);
                r.w = fmaf(0.7f, old.w, 0.3f * r.w);
            }
            *reinterpret_cast<float4*>(hp + i) = r;
        }
    }
}

// decoder agg: 64 features; quarter handles edge e+q, lane reads f16x4 (8B).
__global__ __launch_bounds__(256) void k_agg64v(const __half* __restrict__ t,
                                                const int* __restrict__ rp,
                                                const int2* __restrict__ ews,
                                                const float* __restrict__ bias,
                                                float* __restrict__ out) {
    int node = (blockIdx.x * 256 + threadIdx.x) >> 6;
    if (node >= N_NODES) return;
    const int lane = threadIdx.x & 63;
    const int q  = lane >> 4;
    const int fl = lane & 15;        // feature block (4 features)
    const int e0 = rp[node], e1 = rp[node + 1];

    float acc[4];
    #pragma unroll
    for (int i = 0; i < 4; ++i) acc[i] = 0.f;

    int e = e0;
    for (; e + 7 < e1; e += 8) {
        int2 ewA = ews[e + q];
        int2 ewB = ews[e + 4 + q];
        f16x4 vA = *reinterpret_cast<const f16x4*>(&t[(size_t)ewA.x * 64 + fl * 4]);
        f16x4 vB = *reinterpret_cast<const f16x4*>(&t[(size_t)ewB.x * 64 + fl * 4]);
        float wA = __int_as_float(ewA.y);
        float wB = __int_as_float(ewB.y);
        #pragma unroll
        for (int i = 0; i < 4; ++i) acc[i] = fmaf((float)vA[i], wA, acc[i]);
        #pragma unroll
        for (int i = 0; i < 4; ++i) acc[i] = fmaf((float)vB[i], wB, acc[i]);
    }
    for (; e < e1; e += 4) {
        int idx = e + q;
        bool ok = idx < e1;
        idx = ok ? idx : e1 - 1;
        int2 ew = ews[idx];
        float w = ok ? __int_as_float(ew.y) : 0.f;
        f16x4 v = *reinterpret_cast<const f16x4*>(&t[(size_t)ew.x * 64 + fl * 4]);
        #pragma unroll
        for (int i = 0; i < 4; ++i) acc[i] = fmaf((float)v[i], w, acc[i]);
    }

    #pragma unroll
    for (int i = 0; i < 4; ++i) {
        acc[i] += __shfl_xor(acc[i], 16);
        acc[i] += __shfl_xor(acc[i], 32);
    }

    if (q == 0) {
        const float* bp = &bias[fl * 4];
        float4 b4 = *reinterpret_cast<const float4*>(bp);
        float4 r = make_float4(acc[0] + b4.x, acc[1] + b4.y,
                               acc[2] + b4.z, acc[3] + b4.w);
        *reinterpret_cast<float4*>(&out[(size_t)node * 64 + fl * 4]) = r;
    }
}

// ---------------- host ----------------

extern "C" void kernel_launch(void* const* d_in, const int* in_sizes, int n_in,
                              void* d_out, int out_size, void* d_ws, size_t ws_size,
                              hipStream_t stream) {
    const float* x     = (const float*)d_in[0];
    const int*   ei    = (const int*)d_in[1];
    const float* W_enc = (const float*)d_in[2];
    const float* b_enc = (const float*)d_in[3];
    const float* W_gc  = (const float*)d_in[4];
    const float* b_gc  = (const float*)d_in[5];
    const float* W_dec = (const float*)d_in[6];
    const float* b_dec = (const float*)d_in[7];
    float* out = (float*)d_out;

    const int* srcp = ei;
    const int* dstp = ei + N_EDGES;

    char* ws = (char*)d_ws;
    size_t off = 0;
    auto take = [&](size_t bytes) -> char* {
        char* p = ws + off;
        off = (off + bytes + 511) & ~(size_t)511;
        return p;
    };
    float*  dis   = (float*) take((size_t)N_NODES * 4);
    int*    rp    = (int*)   take((size_t)(N_NODES + 1) * 4);
    int*    cur   = (int*)   take((size_t)N_NODES * 4);
    int*    bs    = (int*)   take(32 * 4);
    int2*   ews   = (int2*)  take((size_t)N_TOT * 8);
    __half* th    = (__half*)take((size_t)N_NODES * 128 * 2);  // fp16 transform buffer
    __half* td    = (__half*)take((size_t)N_NODES * 64 * 2);   // fp16 decoder transform
    float*  hbuf  = (float*) take((size_t)N_NODES * 128 * 4);
    __half* Wt_e  = (__half*)take((size_t)128 * 256 * 2);      // enc  W fp16 col-major
    __half* Wt_g  = (__half*)take((size_t)128 * 128 * 2);      // gc   W fp16 col-major
    __half* Wt_d  = (__half*)take((size_t)64  * 128 * 2);      // dec  W fp16 col-major

    dim3 blk(256);
    int gN = (N_NODES + 255) / 256;
    int gE = (N_EDGES + 255) / 256;
    int gT = (N_TOT + 255) / 256;

    // CSR build (per call — d_ws is re-poisoned before every launch)
    k_init_deg<<<gN, blk, 0, stream>>>(cur);
    k_hist<<<gE, blk, 0, stream>>>(dstp, cur);
    k_dis<<<gN, blk, 0, stream>>>(cur, dis);
    k_scan1<<<25, blk, 0, stream>>>(cur, rp, bs);
    k_scan2<<<1, 64, 0, stream>>>(bs, 25);
    k_scan3<<<gN, blk, 0, stream>>>(rp, bs);
    k_setcur<<<gN, blk, 0, stream>>>(rp, cur);
    k_fill<<<gT, blk, 0, stream>>>(srcp, dstp, dis, cur, ews);

    // W pre-convert (fp32 -> fp16 col-major), once per call
    k_wt<<<(256 * 128 + 255) / 256, blk, 0, stream>>>(W_enc, Wt_e, 256, 128);
    k_wt<<<(128 * 128 + 255) / 256, blk, 0, stream>>>(W_gc,  Wt_g, 128, 128);
    k_wt<<<(128 * 64  + 255) / 256, blk, 0, stream>>>(W_dec, Wt_d, 128, 64);

    int gemmG = (N_NODES + 63) / 64;
    int aggG  = (N_NODES * 64 + 255) / 256;

    // encoder: h = relu(agg(x @ W_enc) + b_enc)
    k_gemm_mfma<256, 128><<<gemmG, blk, 0, stream>>>(x, Wt_e, th);
    k_agg128v<0><<<aggG, blk, 0, stream>>>(th, rp, ews, b_enc, hbuf);

    // 8 smoothing iterations: h = 0.7h + 0.3 relu(agg(h @ W_gc) + b_gc)
    for (int it = 0; it < 8; ++it) {
        k_gemm_mfma<128, 128><<<gemmG, blk, 0, stream>>>(hbuf, Wt_g, th);
        k_agg128v<1><<<aggG, blk, 0, stream>>>(th, rp, ews, b_gc, hbuf);
    }

    // decoder: out = agg(h @ W_dec) + b_dec
    k_gemm_mfma<128, 64><<<gemmG, blk, 0, stream>>>(hbuf, Wt_d, td);
    k_agg64v<<<aggG, blk, 0, stream>>>(td, rp, ews, b_dec, out);
}